// Round 15
// baseline (1231.733 us; speedup 1.0000x reference)
//
#include <hip/hip_runtime.h>

typedef float  __attribute__((ext_vector_type(4))) f32x4;
typedef int    __attribute__((ext_vector_type(4))) i32x4;
typedef unsigned short u16;
typedef unsigned long long u64;

#define B    256
#define H    512
#define HIN  128
#define N    16384
#define RW   16
#define HT   32
#define KC2  672          // 160 (Hg|Ht) + 512 (h) — Wfull K
#define RWN  262144       // RW*N
#define TS_OFF   67108864 // B*RW*N
#define PROB_OFF 67112960 // TS_OFF + B*RW

// ---------- helpers ----------
__device__ __forceinline__ u16 f2bf(float f) {
  unsigned u = __builtin_bit_cast(unsigned, f);
  u += 0x7FFFu + ((u >> 16) & 1u);         // RTNE
  return (u16)(u >> 16);
}
__device__ __forceinline__ float bf2f(u16 v) {
  return __builtin_bit_cast(float, ((unsigned)v) << 16);
}
__device__ __forceinline__ float sigm(float x) { return 1.0f / (1.0f + expf(-x)); }

// NON-volatile asm: "+v" data deps keep ordering & liveness; scheduler may
// hoist loads across MFMAs and software-pipeline the K-loop.
__device__ __forceinline__ void mfma(f32x4& d, i32x4 a, i32x4 b) {
  asm("v_mfma_f32_16x16x32_bf16 %0, %1, %2, %0" : "+v"(d) : "v"(a), "v"(b));
}
// s_nop stays INSIDE the asm so it remains glued to its MFMA under scheduling.
__device__ __forceinline__ void mfma_n(f32x4& d, i32x4 a, i32x4 b) {
  asm("s_nop 1\n\tv_mfma_f32_16x16x32_bf16 %0, %1, %2, %0" : "+v"(d) : "v"(a), "v"(b));
}
__device__ __forceinline__ void fence_acc(f32x4& v) {
  asm("s_nop 7\n\ts_nop 7" : "+v"(v));
}

// ---------- prologue ----------
__global__ __launch_bounds__(256) void k_prep(
    const float* __restrict__ W_up, const float* __restrict__ W_down,
    const float* __restrict__ W_hh, const float* __restrict__ Wt_down,
    const float* __restrict__ b_ih, const float* __restrict__ b_hh,
    const float* __restrict__ Wh, const float* __restrict__ Wcc,
    u16* __restrict__ Wup_b, u16* __restrict__ Wdn_b, u16* __restrict__ Wfull,
    u16* __restrict__ Wtd_b, u16* __restrict__ Whc_b,
    float* __restrict__ bcomb, float* __restrict__ tstep, float* __restrict__ rowLs)
{
  const int idx0 = blockIdx.x * 256 + threadIdx.x;
  const int stride = gridDim.x * 256;
  for (int i = idx0; i < N * H; i += stride) Wup_b[i] = f2bf(W_up[i]);
  for (int i = idx0; i < HIN * N; i += stride) Wdn_b[i] = f2bf(W_down[i]);
  for (int i = idx0; i < 4 * H * H; i += stride) {
    int j = i >> 9, k = i & 511;
    Wfull[j * KC2 + 160 + k] = f2bf(W_hh[i]);
  }
  for (int i = idx0; i < HT * H; i += stride) Wtd_b[i] = f2bf(Wt_down[i]);
  for (int i = idx0; i < 2 * H * H; i += stride) {
    int j = i >> 9, k = i & 511;
    Whc_b[i] = f2bf(j < H ? Wh[j * H + k] : Wcc[(j - H) * H + k]);
  }
  for (int i = idx0; i < 4 * H; i += stride) bcomb[i] = b_ih[i] + b_hh[i];
  for (int i = idx0; i < B; i += stride) tstep[i] = 0.0f;
  for (int i = idx0; i < 16 * B; i += stride) rowLs[i] = 0.0f;
}

// Wcomb = W_ih @ W_vt into Wfull cols 0..159; g0add = inputs0 @ W_ih^T; wpc = W_prob @ W_vt
__global__ __launch_bounds__(256) void k_fold(
    const float* __restrict__ W_ih, const float* __restrict__ W_vt,
    const float* __restrict__ inputs0, const float* __restrict__ W_prob,
    u16* __restrict__ Wfull, float* __restrict__ g0add, float* __restrict__ wpc)
{
  int idx = blockIdx.x * 256 + threadIdx.x;
  if (idx < 2048 * 160) {
    int j = idx / 160, m = idx - j * 160;
    float a = 0.0f;
    for (int c = 0; c < HIN; ++c) a += W_ih[j * HIN + c] * W_vt[c * 160 + m];
    Wfull[j * KC2 + m] = f2bf(a);
  } else if (idx < 2048 * 160 + 256 * 2048) {
    int i2 = idx - 2048 * 160;
    int b = i2 >> 11, j = i2 & 2047;
    float a = 0.0f;
    for (int k = 0; k < HIN; ++k) a += inputs0[b * HIN + k] * W_ih[j * HIN + k];
    g0add[i2] = a;
  } else if (idx < 2048 * 160 + 256 * 2048 + 160) {
    int m = idx - (2048 * 160 + 256 * 2048);
    float a = 0.0f;
    for (int k = 0; k < HIN; ++k) a += W_prob[k] * W_vt[k * 160 + m];
    wpc[m] = a;
  }
}

__global__ __launch_bounds__(256) void k_lat(
    const float* __restrict__ latent, const float* __restrict__ Wc,
    const float* __restrict__ bc, float* __restrict__ latbuf)
{
  int idx = blockIdx.x * 256 + threadIdx.x;
  int b = idx >> 7, i = idx & 127;
  float acc = bc[i];
  for (int k = 0; k < 129; ++k) acc += latent[b * 129 + k] * Wc[i * 129 + k];
  latbuf[idx] = tanhf(acc);
}

__global__ __launch_bounds__(256) void k_sinit(
    const float* __restrict__ latbuf, const float* __restrict__ Ws,
    const float* __restrict__ bs, u16* __restrict__ sinit_b)
{
  int idx = blockIdx.x * 256 + threadIdx.x;
  int b = idx >> 9, j = idx & 511;
  float acc = bs[j];
  for (int k = 0; k < HIN; ++k) acc += latbuf[b * HIN + k] * Ws[j * HIN + k];
  sinit_b[idx] = f2bf(tanhf(acc));
}

// h0/c0 via MFMA: h0 -> hbuf1 [256][512] bf16, c0 -> cbuf f32
__global__ __launch_bounds__(256) void k_h0c0m(
    const u16* __restrict__ sinit_b, const u16* __restrict__ Whc_b,
    const float* __restrict__ bh, const float* __restrict__ bcc,
    float* __restrict__ cbuf, u16* __restrict__ h0out)
{
  const int rb = blockIdx.x >> 6, cb = blockIdx.x & 63;
  const int wave = threadIdx.x >> 6, lane = threadIdx.x & 63;
  const int lr = lane & 15, lk = lane >> 4;
  const int m0 = rb * 16, col0 = cb * 16;
  const u16* ab = sinit_b + (m0 + lr) * H + wave * 128 + 8 * lk;
  const u16* bb = Whc_b + (col0 + lr) * H + wave * 128 + 8 * lk;
  f32x4 acc[2] = {};
  mfma_n(acc[0], *(const i32x4*)(ab),      *(const i32x4*)(bb));
  mfma_n(acc[1], *(const i32x4*)(ab + 32), *(const i32x4*)(bb + 32));
  mfma(acc[0], *(const i32x4*)(ab + 64), *(const i32x4*)(bb + 64));
  mfma(acc[1], *(const i32x4*)(ab + 96), *(const i32x4*)(bb + 96));
  fence_acc(acc[0]); fence_acc(acc[1]);
  __shared__ float q[4][16][17];
  #pragma unroll
  for (int rr = 0; rr < 4; ++rr)
    q[wave][4 * lk + rr][lr] = acc[0][rr] + acc[1][rr];
  __syncthreads();
  const int r2 = threadIdx.x >> 4, jj = threadIdx.x & 15;
  float s = q[0][r2][jj] + q[1][r2][jj] + q[2][r2][jj] + q[3][r2][jj];
  int col = col0 + jj;
  if (col < H) h0out[(m0 + r2) * H + col] = f2bf(tanhf(s + bh[col]));
  else         cbuf[(m0 + r2) * H + col - H] = tanhf(s + bcc[col - H]);
}

// ---------- per-step K1: finish step r-1 (t-constraint, Hgf read+scale, v-normalize)
//            + gates GEMM (A = [Hg|Ht] from LDS, h from global) + LSTM pointwise
__global__ __launch_bounds__(256) void k_lstm2(
    const u16* __restrict__ hprev, u16* __restrict__ hcur,
    const u16* __restrict__ Wfull, const float* __restrict__ bcomb,
    float* __restrict__ cbuf, const float* __restrict__ g0,
    const float* __restrict__ HgfPrev, float* __restrict__ HgfNext,
    const float* __restrict__ rowLs, const float* __restrict__ t0buf,
    float* __restrict__ tstep, const float* __restrict__ Wt_up,
    const float* __restrict__ bt_up, float* __restrict__ out,
    const u16* __restrict__ ebp, int r)
{
  const int blk = blockIdx.x, tid = threadIdx.x;
  const int wave = tid >> 6, lane = tid & 63;
  const int lr = lane & 15, lk = lane >> 4;
  const int rb = blk & 15, cb = blk >> 4;
  const int m0 = rb * 16, j0 = cb * 16;
  const float* rowLprev = rowLs + (r - 1) * B;

  __shared__ u16 aT[16][168];
  __shared__ float q[4][16][17];
  __shared__ float redS[8];
  __shared__ float tl[256];

  if (blk < 128) HgfNext[blk * 256 + tid] = 0.0f;

  float tv = 0.0f;
  if (r > 0) {
    tv = t0buf[tid];
    float v = tv;
    #pragma unroll
    for (int off = 1; off < 64; off <<= 1) v = fminf(v, __shfl_xor(v, off));
    if (lane == 0) redS[wave] = v;
  }
  __syncthreads();
  if (r > 0) {
    float mn = fminf(fminf(redS[0], redS[1]), fminf(redS[2], redS[3]));
    if (mn < 0.1f) tv -= mn;
    float v = tv;
    #pragma unroll
    for (int off = 1; off < 64; off <<= 1) v = fmaxf(v, __shfl_xor(v, off));
    if (lane == 0) redS[4 + wave] = v;
  }
  __syncthreads();
  if (r > 0) {
    float mx = fmaxf(fmaxf(redS[4], redS[5]), fmaxf(redS[6], redS[7]));
    if (mx > 1.0f) tv /= mx;
    tv = fminf(fmaxf(tv, tstep[(r - 1) * B + tid]), 1.0f);
    if (blk == 0) {
      tstep[r * B + tid] = tv;
      out[TS_OFF + tid * RW + (r - 1)] = tv;
    }
  }
  tl[tid] = tv;

  {
    const int row = tid >> 4, c8 = (tid & 15) * 8;
    if (r > 0) {
      const float* hp = HgfPrev + (m0 + row) * HIN + c8;
      f32x4 x0 = *(const f32x4*)hp;
      f32x4 x1 = *(const f32x4*)(hp + 4);
      float R = 1.0f / rowLprev[m0 + row];
      aT[row][c8 + 0] = f2bf(x0[0] * R); aT[row][c8 + 1] = f2bf(x0[1] * R);
      aT[row][c8 + 2] = f2bf(x0[2] * R); aT[row][c8 + 3] = f2bf(x0[3] * R);
      aT[row][c8 + 4] = f2bf(x1[0] * R); aT[row][c8 + 5] = f2bf(x1[1] * R);
      aT[row][c8 + 6] = f2bf(x1[2] * R); aT[row][c8 + 7] = f2bf(x1[3] * R);
    } else {
      #pragma unroll
      for (int e = 0; e < 8; ++e) aT[row][c8 + e] = 0;
    }
  }
  __syncthreads();

  for (int i2 = tid; i2 < 512; i2 += 256) {
    int row = i2 >> 5, j = i2 & 31;
    aT[row][128 + j] = (r > 0) ? f2bf(tl[m0 + row] * Wt_up[j] + bt_up[j]) : (u16)0;
  }

  // v-normalize step r-1 (streaming, off critical path)
  if (r > 0) {
    #pragma unroll
    for (int uu = 0; uu < 8; ++uu) {
      int flat = (blk * 2048 + uu * 256 + tid) * 4;
      int row = flat >> 14;
      float Rv = 1.0f / rowLprev[row];
      u64 ev = *(const u64*)(ebp + flat);
      f32x4 o;
      o[0] = bf2f((u16)ev) * Rv;
      o[1] = bf2f((u16)(ev >> 16)) * Rv;
      o[2] = bf2f((u16)(ev >> 32)) * Rv;
      o[3] = bf2f((u16)(ev >> 48)) * Rv;
      *(f32x4*)(out + (size_t)row * RWN + (size_t)(r - 1) * N + (flat & (N - 1))) = o;
    }
  }
  __syncthreads();

  // gates GEMM: K = 160 (LDS aT) + 512 (global hprev)
  const int gcol = wave * H + j0 + lr;
  f32x4 acc[2] = {};
  const u16* brow = Wfull + (size_t)gcol * KC2 + 8 * lk;
  const u16* aL   = &aT[lr][8 * lk];
  const u16* arow = hprev + (m0 + lr) * H + 8 * lk;
  mfma_n(acc[0], *(const i32x4*)(aL),       *(const i32x4*)(brow));
  mfma_n(acc[1], *(const i32x4*)(aL + 32),  *(const i32x4*)(brow + 32));
  mfma(acc[0], *(const i32x4*)(aL + 64),  *(const i32x4*)(brow + 64));
  mfma(acc[1], *(const i32x4*)(aL + 96),  *(const i32x4*)(brow + 96));
  mfma(acc[0], *(const i32x4*)(aL + 128), *(const i32x4*)(brow + 128));
  #pragma unroll 8
  for (int i = 5; i < 21; ++i) {
    int kk = i * 32;
    mfma(acc[i & 1], *(const i32x4*)(arow + kk - 160), *(const i32x4*)(brow + kk));
  }
  fence_acc(acc[0]); fence_acc(acc[1]);
  float bias = bcomb[gcol];
  #pragma unroll
  for (int rr = 0; rr < 4; ++rr)
    q[wave][4 * lk + rr][lr] = acc[0][rr] + acc[1][rr] + bias;
  __syncthreads();
  const int r2 = tid >> 4, jj = tid & 15;
  const int b = m0 + r2, j = j0 + jj;
  float gi = q[0][r2][jj], gf = q[1][r2][jj], gg = q[2][r2][jj], go = q[3][r2][jj];
  if (r == 0) {
    const float* gp = g0 + b * 2048 + j;
    gi += gp[0]; gf += gp[512]; gg += gp[1024]; go += gp[1536];
  }
  float c  = cbuf[b * H + j];
  float c2 = sigm(gf) * c + sigm(gi) * tanhf(gg);
  float h2 = sigm(go) * tanhf(c2);
  cbuf[b * H + j] = c2;
  hcur[b * H + j] = f2bf(h2);
}

// ---------- per-step K2: p GEMM -> e bf16 + rowL atomics + Hg atomics + straggler
// grid 1024 = 8 rb(32 rows) x 128 cb(128 cols); wave covers 32 cols.
__global__ __launch_bounds__(256) void k_pgemm2(
    const u16* __restrict__ hb, const u16* __restrict__ Wup,
    const float* __restrict__ b_up, const float* __restrict__ gum,
    u16* __restrict__ eb, float* __restrict__ rowL,
    float* __restrict__ HgfAcc, const u16* __restrict__ Wdn,
    const u16* __restrict__ Wtd, const float* __restrict__ bt_down,
    const float* __restrict__ Wt_pred, const float* __restrict__ du,
    float* __restrict__ t0)
{
  const int rb = blockIdx.x >> 7, cb = blockIdx.x & 127;
  const int wave = threadIdx.x >> 6, lane = threadIdx.x & 63;
  const int lr = lane & 15, lk = lane >> 4;
  const int m0 = rb * 32;
  const int n0 = cb * 128 + wave * 32;

  // prefetch gumbel + bias early: HBM latency hides under the K-loop MFMAs
  float gv[2][4][2], bup0 = b_up[n0 + lr], bup1 = b_up[n0 + 16 + lr];
  #pragma unroll
  for (int mi = 0; mi < 2; ++mi)
    #pragma unroll
    for (int rr = 0; rr < 4; ++rr) {
      int row = m0 + 16 * mi + 4 * lk + rr;
      gv[mi][rr][0] = gum[(size_t)row * N + n0 + lr];
      gv[mi][rr][1] = gum[(size_t)row * N + n0 + 16 + lr];
    }

  f32x4 acc[2][2] = {};
  const u16* a0 = hb + (m0 + lr) * H + 8 * lk;
  const u16* a1 = a0 + 16 * H;
  const u16* b0 = Wup + (size_t)(n0 + lr) * H + 8 * lk;
  const u16* b1 = b0 + 16 * H;
  {
    i32x4 af0 = *(const i32x4*)(a0);
    i32x4 af1 = *(const i32x4*)(a1);
    i32x4 bf0 = *(const i32x4*)(b0);
    i32x4 bf1 = *(const i32x4*)(b1);
    mfma_n(acc[0][0], af0, bf0); mfma_n(acc[0][1], af0, bf1);
    mfma_n(acc[1][0], af1, bf0); mfma_n(acc[1][1], af1, bf1);
  }
  #pragma unroll 6
  for (int kk = 32; kk < H; kk += 32) {
    i32x4 af0 = *(const i32x4*)(a0 + kk);
    i32x4 af1 = *(const i32x4*)(a1 + kk);
    i32x4 bf0 = *(const i32x4*)(b0 + kk);
    i32x4 bf1 = *(const i32x4*)(b1 + kk);
    mfma(acc[0][0], af0, bf0); mfma(acc[0][1], af0, bf1);
    mfma(acc[1][0], af1, bf0); mfma(acc[1][1], af1, bf1);
  }
  #pragma unroll
  for (int mi = 0; mi < 2; ++mi) { fence_acc(acc[mi][0]); fence_acc(acc[mi][1]); }

  __shared__ u16 eLb[32][136];
  __shared__ float sL[4][32];
  #pragma unroll
  for (int mi = 0; mi < 2; ++mi)
    #pragma unroll
    for (int rr = 0; rr < 4; ++rr) {
      int rl = 16 * mi + 4 * lk + rr;
      int row = m0 + rl;
      u16* sp = eb + (size_t)row * N + n0 + lr;
      float v0 = acc[mi][0][rr] + bup0 + gv[mi][rr][0];
      float v1 = acc[mi][1][rr] + bup1 + gv[mi][rr][1];
      float e0 = expf(fminf(v0, 80.0f));
      float e1 = expf(fminf(v1, 80.0f));
      u16 p0 = f2bf(e0), p1 = f2bf(e1);
      sp[0] = p0; sp[16] = p1;
      eLb[rl][wave * 32 + lr] = p0;
      eLb[rl][wave * 32 + 16 + lr] = p1;
      float par = e0 + e1;
      #pragma unroll
      for (int off = 1; off < 16; off <<= 1) par += __shfl_xor(par, off);
      if (lr == 0) sL[wave][rl] = par;
    }
  __syncthreads();
  if (threadIdx.x < 32)
    atomicAdd(rowL + m0 + threadIdx.x,
              sL[0][threadIdx.x] + sL[1][threadIdx.x] + sL[2][threadIdx.x] + sL[3][threadIdx.x]);

  // Hg partial GEMM over this block's K-slab -> f32 atomics into HgfAcc (L2-resident)
  const int nb = cb * 128;
  f32x4 acc2[2][2] = {};
  #pragma unroll
  for (int kk2 = 0; kk2 < 4; ++kk2) {
    i32x4 af0 = *(const i32x4*)(&eLb[lr][kk2 * 32 + 8 * lk]);
    i32x4 af1 = *(const i32x4*)(&eLb[16 + lr][kk2 * 32 + 8 * lk]);
    i32x4 bf0 = *(const i32x4*)(Wdn + (size_t)(wave * 32 + lr) * N + nb + kk2 * 32 + 8 * lk);
    i32x4 bf1 = *(const i32x4*)(Wdn + (size_t)(wave * 32 + 16 + lr) * N + nb + kk2 * 32 + 8 * lk);
    mfma(acc2[0][0], af0, bf0); mfma(acc2[0][1], af0, bf1);
    mfma(acc2[1][0], af1, bf0); mfma(acc2[1][1], af1, bf1);
  }
  #pragma unroll
  for (int mi2 = 0; mi2 < 2; ++mi2) { fence_acc(acc2[mi2][0]); fence_acc(acc2[mi2][1]); }
  #pragma unroll
  for (int mi2 = 0; mi2 < 2; ++mi2)
    #pragma unroll
    for (int ni = 0; ni < 2; ++ni)
      #pragma unroll
      for (int rr = 0; rr < 4; ++rr)
        atomicAdd(HgfAcc + (m0 + 16 * mi2 + 4 * lk + rr) * HIN + wave * 32 + 16 * ni + lr,
                  acc2[mi2][ni][rr]);

  // straggler: td = tanh(h2 @ Wt_down^T + bt)*mask/keep ; t0 = min(td @ Wt_pred^T, 1)
  if (cb == 0 && wave < 2) {
    f32x4 acc3[2] = {};
    const u16* at = hb + (m0 + wave * 16 + lr) * H + 8 * lk;
    {
      i32x4 af = *(const i32x4*)(at);
      mfma_n(acc3[0], af, *(const i32x4*)(Wtd + lr * H + 8 * lk));
      mfma_n(acc3[1], af, *(const i32x4*)(Wtd + (16 + lr) * H + 8 * lk));
    }
    for (int kk = 32; kk < H; kk += 32) {
      i32x4 af = *(const i32x4*)(at + kk);
      mfma(acc3[0], af, *(const i32x4*)(Wtd + lr * H + kk + 8 * lk));
      mfma(acc3[1], af, *(const i32x4*)(Wtd + (16 + lr) * H + kk + 8 * lk));
    }
    fence_acc(acc3[0]); fence_acc(acc3[1]);
    float wp0 = Wt_pred[lr],  wp1 = Wt_pred[16 + lr];
    float bt0 = bt_down[lr],  bt1 = bt_down[16 + lr];
    #pragma unroll
    for (int rr = 0; rr < 4; ++rr) {
      int row = m0 + wave * 16 + 4 * lk + rr;
      float td0 = tanhf(acc3[0][rr] + bt0);
      float td1 = tanhf(acc3[1][rr] + bt1);
      td0 = (du[row * HT + lr]      < 0.8f) ? td0 * 1.25f : 0.0f;
      td1 = (du[row * HT + 16 + lr] < 0.8f) ? td1 * 1.25f : 0.0f;
      float part = td0 * wp0 + td1 * wp1;
      #pragma unroll
      for (int off = 1; off < 16; off <<= 1) part += __shfl_xor(part, off);
      if (lr == 0) t0[row] = fminf(part, 1.0f);
    }
  }
}

// ---------- tail: normalize step 15 + t15 finish ----------
__global__ __launch_bounds__(256) void k_tail(
    float* __restrict__ out, const u16* __restrict__ eb15,
    const float* __restrict__ rowLs, const float* __restrict__ t0buf,
    float* __restrict__ tstep)
{
  const int blk = blockIdx.x, tid = threadIdx.x;
  const float* rowL15 = rowLs + 15 * B;
  #pragma unroll
  for (int uu = 0; uu < 4; ++uu) {
    int flat = (blk * 1024 + uu * 256 + tid) * 4;
    int row = flat >> 14;
    float Rv = 1.0f / rowL15[row];
    u64 ev = *(const u64*)(eb15 + flat);
    f32x4 o;
    o[0] = bf2f((u16)ev) * Rv;
    o[1] = bf2f((u16)(ev >> 16)) * Rv;
    o[2] = bf2f((u16)(ev >> 32)) * Rv;
    o[3] = bf2f((u16)(ev >> 48)) * Rv;
    *(f32x4*)(out + (size_t)row * RWN + (size_t)15 * N + (flat & (N - 1))) = o;
  }
  if (blk == 0) {
    const int wave = tid >> 6, lane = tid & 63;
    __shared__ float redS[8];
    float tv = t0buf[tid];
    float v = tv;
    #pragma unroll
    for (int off = 1; off < 64; off <<= 1) v = fminf(v, __shfl_xor(v, off));
    if (lane == 0) redS[wave] = v;
    __syncthreads();
    float mn = fminf(fminf(redS[0], redS[1]), fminf(redS[2], redS[3]));
    if (mn < 0.1f) tv -= mn;
    v = tv;
    #pragma unroll
    for (int off = 1; off < 64; off <<= 1) v = fmaxf(v, __shfl_xor(v, off));
    if (lane == 0) redS[4 + wave] = v;
    __syncthreads();
    float mx = fmaxf(fmaxf(redS[4], redS[5]), fmaxf(redS[6], redS[7]));
    if (mx > 1.0f) tv /= mx;
    tv = fminf(fmaxf(tv, tstep[15 * B + tid]), 1.0f);
    tstep[16 * B + tid] = tv;
    out[TS_OFF + tid * RW + 15] = tv;
  }
}

__global__ __launch_bounds__(256) void k_prob(
    const float* __restrict__ Hgf15, const float* __restrict__ rowLs,
    const float* __restrict__ tstep, const float* __restrict__ Wt_up,
    const float* __restrict__ bt_up, const float* __restrict__ wpc,
    float* __restrict__ outp)
{
  int b = threadIdx.x;
  float R = 1.0f / rowLs[15 * B + b];
  float acc = 0.0f;
  for (int m = 0; m < HIN; ++m) acc += Hgf15[b * HIN + m] * R * wpc[m];
  float tv = tstep[16 * B + b];
  for (int j = 0; j < HT; ++j) acc += (tv * Wt_up[j] + bt_up[j]) * wpc[HIN + j];
  outp[b] = acc;
}

// ---------- launch ----------
extern "C" void kernel_launch(void* const* d_in, const int* in_sizes, int n_in,
                              void* d_out, int out_size, void* d_ws, size_t ws_size,
                              hipStream_t stream) {
  (void)in_sizes; (void)n_in; (void)out_size; (void)ws_size;
  const float* latent  = (const float*)d_in[0];
  const float* inputs0 = (const float*)d_in[1];
  const float* Wc      = (const float*)d_in[2];
  const float* bc      = (const float*)d_in[3];
  const float* Ws      = (const float*)d_in[4];
  const float* bs      = (const float*)d_in[5];
  const float* Wh      = (const float*)d_in[6];
  const float* bh      = (const float*)d_in[7];
  const float* Wcc     = (const float*)d_in[8];
  const float* bcc     = (const float*)d_in[9];
  const float* W_ih    = (const float*)d_in[10];
  const float* b_ih    = (const float*)d_in[11];
  const float* W_hh    = (const float*)d_in[12];
  const float* b_hh    = (const float*)d_in[13];
  const float* W_up    = (const float*)d_in[14];
  const float* b_up    = (const float*)d_in[15];
  const float* W_down  = (const float*)d_in[16];
  const float* Wt_down = (const float*)d_in[17];
  const float* bt_down = (const float*)d_in[18];
  const float* Wt_pred = (const float*)d_in[19];
  const float* Wt_up   = (const float*)d_in[20];
  const float* bt_up   = (const float*)d_in[21];
  const float* W_vt    = (const float*)d_in[22];
  const float* W_prob  = (const float*)d_in[23];
  const float* gumbel  = (const float*)d_in[24];
  const float* drop_u  = (const float*)d_in[25];
  float* out = (float*)d_out;

  char* p = (char*)d_ws;
  auto alloc = [&](size_t bytes) { char* r = p; p += (bytes + 255) & ~(size_t)255; return r; };
  u16*   Wup_b  = (u16*)  alloc((size_t)N * H * 2);
  u16*   Wdn_b  = (u16*)  alloc((size_t)HIN * N * 2);
  u16*   Wfull_b= (u16*)  alloc((size_t)4 * H * KC2 * 2);
  u16*   Wtd_b  = (u16*)  alloc((size_t)HT * H * 2);
  u16*   Whc_b  = (u16*)  alloc((size_t)2 * H * H * 2);
  float* bcomb  = (float*)alloc(4 * H * 4);
  u16*   hbuf0  = (u16*)  alloc((size_t)B * H * 2);
  u16*   hbuf1  = (u16*)  alloc((size_t)B * H * 2);
  float* cbuf   = (float*)alloc((size_t)B * H * 4);
  u16*   sinit_b= (u16*)  alloc((size_t)B * H * 2);
  float* latbuf = (float*)alloc((size_t)B * HIN * 4);
  float* rowLs  = (float*)alloc((size_t)16 * B * 4);
  float* t0buf  = (float*)alloc(B * 4);
  float* tstep  = (float*)alloc((size_t)17 * B * 4);
  float* Hgf2_0 = (float*)alloc((size_t)B * HIN * 4);
  float* Hgf2_1 = (float*)alloc((size_t)B * HIN * 4);
  float* g0add  = (float*)alloc((size_t)B * 4 * H * 4);
  float* wpc    = (float*)alloc(160 * 4);
  u16*   ebuf0  = (u16*)  alloc((size_t)B * N * 2);
  u16*   ebuf1  = (u16*)  alloc((size_t)B * N * 2);

  k_prep<<<2048, 256, 0, stream>>>(W_up, W_down, W_hh, Wt_down, b_ih, b_hh, Wh, Wcc,
                                   Wup_b, Wdn_b, Wfull_b, Wtd_b, Whc_b, bcomb,
                                   tstep, rowLs);
  k_fold<<<3330, 256, 0, stream>>>(W_ih, W_vt, inputs0, W_prob, Wfull_b, g0add, wpc);
  k_lat  <<<128, 256, 0, stream>>>(latent, Wc, bc, latbuf);
  k_sinit<<<512, 256, 0, stream>>>(latbuf, Ws, bs, sinit_b);
  k_h0c0m<<<1024, 256, 0, stream>>>(sinit_b, Whc_b, bh, bcc, cbuf, hbuf1);

  for (int r = 0; r < 16; ++r) {
    u16* hprev = (r & 1) ? hbuf0 : hbuf1;
    u16* hcur  = (r & 1) ? hbuf1 : hbuf0;
    u16* eb    = (r & 1) ? ebuf1 : ebuf0;
    u16* ebp   = (r & 1) ? ebuf0 : ebuf1;
    float* HgfCur  = (r & 1) ? Hgf2_1 : Hgf2_0;
    float* HgfPrev = (r & 1) ? Hgf2_0 : Hgf2_1;
    k_lstm2<<<512, 256, 0, stream>>>(hprev, hcur, Wfull_b, bcomb, cbuf, g0add,
                                     HgfPrev, HgfCur, rowLs, t0buf, tstep,
                                     Wt_up, bt_up, out, ebp, r);
    k_pgemm2<<<1024, 256, 0, stream>>>(hcur, Wup_b, b_up, gumbel + (size_t)r * B * N,
                                       eb, rowLs + r * B, HgfCur, Wdn_b,
                                       Wtd_b, bt_down, Wt_pred,
                                       drop_u + (size_t)r * B * HT, t0buf);
  }
  k_tail<<<1024, 256, 0, stream>>>(out, ebuf1, rowLs, t0buf, tstep);
  k_prob<<<1, 256, 0, stream>>>(Hgf2_1, rowLs, tstep, Wt_up, bt_up, wpc, out + PROB_OFF);
}

// Round 16
// 1174.755 us; speedup vs baseline: 1.0485x; 1.0485x over previous
//
#include <hip/hip_runtime.h>

typedef float  __attribute__((ext_vector_type(4))) f32x4;
typedef int    __attribute__((ext_vector_type(4))) i32x4;
typedef unsigned short u16;
typedef unsigned long long u64;

#define B    256
#define H    512
#define HIN  128
#define N    16384
#define RW   16
#define HT   32
#define KC2  672          // 160 (Hg|Ht) + 512 (h) — Wfull K
#define RWN  262144       // RW*N
#define TS_OFF   67108864 // B*RW*N
#define PROB_OFF 67112960 // TS_OFF + B*RW

// ---------- helpers ----------
__device__ __forceinline__ u16 f2bf(float f) {
  unsigned u = __builtin_bit_cast(unsigned, f);
  u += 0x7FFFu + ((u >> 16) & 1u);         // RTNE
  return (u16)(u >> 16);
}
__device__ __forceinline__ float bf2f(u16 v) {
  return __builtin_bit_cast(float, ((unsigned)v) << 16);
}
__device__ __forceinline__ float sigm(float x) { return 1.0f / (1.0f + expf(-x)); }

// NON-volatile asm: "+v" data deps keep ordering & liveness; scheduler may
// hoist loads across MFMAs and software-pipeline the K-loop.  (R13 champion)
__device__ __forceinline__ void mfma(f32x4& d, i32x4 a, i32x4 b) {
  asm("v_mfma_f32_16x16x32_bf16 %0, %1, %2, %0" : "+v"(d) : "v"(a), "v"(b));
}
// s_nop stays INSIDE the asm so it remains glued to its MFMA under scheduling.
__device__ __forceinline__ void mfma_n(f32x4& d, i32x4 a, i32x4 b) {
  asm("s_nop 1\n\tv_mfma_f32_16x16x32_bf16 %0, %1, %2, %0" : "+v"(d) : "v"(a), "v"(b));
}
__device__ __forceinline__ void fence_acc(f32x4& v) {
  asm("s_nop 7\n\ts_nop 7" : "+v"(v));
}

// ---------- prologue ----------
__global__ __launch_bounds__(256) void k_prep(
    const float* __restrict__ W_up, const float* __restrict__ W_down,
    const float* __restrict__ W_hh, const float* __restrict__ Wt_down,
    const float* __restrict__ b_ih, const float* __restrict__ b_hh,
    const float* __restrict__ Wh, const float* __restrict__ Wcc,
    u16* __restrict__ Wup_b, u16* __restrict__ Wdn_b, u16* __restrict__ Wfull,
    u16* __restrict__ Wtd_b, u16* __restrict__ Whc_b,
    float* __restrict__ bcomb, float* __restrict__ tstep, float* __restrict__ rowLs)
{
  const int idx0 = blockIdx.x * 256 + threadIdx.x;
  const int stride = gridDim.x * 256;
  for (int i = idx0; i < N * H; i += stride) Wup_b[i] = f2bf(W_up[i]);
  for (int i = idx0; i < HIN * N; i += stride) Wdn_b[i] = f2bf(W_down[i]);
  for (int i = idx0; i < 4 * H * H; i += stride) {
    int j = i >> 9, k = i & 511;
    Wfull[j * KC2 + 160 + k] = f2bf(W_hh[i]);
  }
  for (int i = idx0; i < HT * H; i += stride) Wtd_b[i] = f2bf(Wt_down[i]);
  for (int i = idx0; i < 2 * H * H; i += stride) {
    int j = i >> 9, k = i & 511;
    Whc_b[i] = f2bf(j < H ? Wh[j * H + k] : Wcc[(j - H) * H + k]);
  }
  for (int i = idx0; i < 4 * H; i += stride) bcomb[i] = b_ih[i] + b_hh[i];
  for (int i = idx0; i < B; i += stride) tstep[i] = 0.0f;
  for (int i = idx0; i < 16 * B; i += stride) rowLs[i] = 0.0f;
}

// Wcomb = W_ih @ W_vt into Wfull cols 0..159; g0add = inputs0 @ W_ih^T; wpc = W_prob @ W_vt
__global__ __launch_bounds__(256) void k_fold(
    const float* __restrict__ W_ih, const float* __restrict__ W_vt,
    const float* __restrict__ inputs0, const float* __restrict__ W_prob,
    u16* __restrict__ Wfull, float* __restrict__ g0add, float* __restrict__ wpc)
{
  int idx = blockIdx.x * 256 + threadIdx.x;
  if (idx < 2048 * 160) {
    int j = idx / 160, m = idx - j * 160;
    float a = 0.0f;
    for (int c = 0; c < HIN; ++c) a += W_ih[j * HIN + c] * W_vt[c * 160 + m];
    Wfull[j * KC2 + m] = f2bf(a);
  } else if (idx < 2048 * 160 + 256 * 2048) {
    int i2 = idx - 2048 * 160;
    int b = i2 >> 11, j = i2 & 2047;
    float a = 0.0f;
    for (int k = 0; k < HIN; ++k) a += inputs0[b * HIN + k] * W_ih[j * HIN + k];
    g0add[i2] = a;
  } else if (idx < 2048 * 160 + 256 * 2048 + 160) {
    int m = idx - (2048 * 160 + 256 * 2048);
    float a = 0.0f;
    for (int k = 0; k < HIN; ++k) a += W_prob[k] * W_vt[k * 160 + m];
    wpc[m] = a;
  }
}

__global__ __launch_bounds__(256) void k_lat(
    const float* __restrict__ latent, const float* __restrict__ Wc,
    const float* __restrict__ bc, float* __restrict__ latbuf)
{
  int idx = blockIdx.x * 256 + threadIdx.x;
  int b = idx >> 7, i = idx & 127;
  float acc = bc[i];
  for (int k = 0; k < 129; ++k) acc += latent[b * 129 + k] * Wc[i * 129 + k];
  latbuf[idx] = tanhf(acc);
}

__global__ __launch_bounds__(256) void k_sinit(
    const float* __restrict__ latbuf, const float* __restrict__ Ws,
    const float* __restrict__ bs, u16* __restrict__ sinit_b)
{
  int idx = blockIdx.x * 256 + threadIdx.x;
  int b = idx >> 9, j = idx & 511;
  float acc = bs[j];
  for (int k = 0; k < HIN; ++k) acc += latbuf[b * HIN + k] * Ws[j * HIN + k];
  sinit_b[idx] = f2bf(tanhf(acc));
}

// h0/c0 via MFMA: h0 -> hbuf1 [256][512] bf16, c0 -> cbuf f32
__global__ __launch_bounds__(256) void k_h0c0m(
    const u16* __restrict__ sinit_b, const u16* __restrict__ Whc_b,
    const float* __restrict__ bh, const float* __restrict__ bcc,
    float* __restrict__ cbuf, u16* __restrict__ h0out)
{
  const int rb = blockIdx.x >> 6, cb = blockIdx.x & 63;
  const int wave = threadIdx.x >> 6, lane = threadIdx.x & 63;
  const int lr = lane & 15, lk = lane >> 4;
  const int m0 = rb * 16, col0 = cb * 16;
  const u16* ab = sinit_b + (m0 + lr) * H + wave * 128 + 8 * lk;
  const u16* bb = Whc_b + (col0 + lr) * H + wave * 128 + 8 * lk;
  f32x4 acc[2] = {};
  mfma_n(acc[0], *(const i32x4*)(ab),      *(const i32x4*)(bb));
  mfma_n(acc[1], *(const i32x4*)(ab + 32), *(const i32x4*)(bb + 32));
  mfma(acc[0], *(const i32x4*)(ab + 64), *(const i32x4*)(bb + 64));
  mfma(acc[1], *(const i32x4*)(ab + 96), *(const i32x4*)(bb + 96));
  fence_acc(acc[0]); fence_acc(acc[1]);
  __shared__ float q[4][16][17];
  #pragma unroll
  for (int rr = 0; rr < 4; ++rr)
    q[wave][4 * lk + rr][lr] = acc[0][rr] + acc[1][rr];
  __syncthreads();
  const int r2 = threadIdx.x >> 4, jj = threadIdx.x & 15;
  float s = q[0][r2][jj] + q[1][r2][jj] + q[2][r2][jj] + q[3][r2][jj];
  int col = col0 + jj;
  if (col < H) h0out[(m0 + r2) * H + col] = f2bf(tanhf(s + bh[col]));
  else         cbuf[(m0 + r2) * H + col - H] = tanhf(s + bcc[col - H]);
}

// ---------- per-step K1: finish step r-1 (t-constraint, Hgf read+scale, v-normalize)
//            + gates GEMM (A = [Hg|Ht] from LDS, h from global) + LSTM pointwise
__global__ __launch_bounds__(256) void k_lstm2(
    const u16* __restrict__ hprev, u16* __restrict__ hcur,
    const u16* __restrict__ Wfull, const float* __restrict__ bcomb,
    float* __restrict__ cbuf, const float* __restrict__ g0,
    const float* __restrict__ HgfPrev, float* __restrict__ HgfNext,
    const float* __restrict__ rowLs, const float* __restrict__ t0buf,
    float* __restrict__ tstep, const float* __restrict__ Wt_up,
    const float* __restrict__ bt_up, float* __restrict__ out,
    const u16* __restrict__ ebp, int r)
{
  const int blk = blockIdx.x, tid = threadIdx.x;
  const int wave = tid >> 6, lane = tid & 63;
  const int lr = lane & 15, lk = lane >> 4;
  const int rb = blk & 15, cb = blk >> 4;
  const int m0 = rb * 16, j0 = cb * 16;
  const float* rowLprev = rowLs + (r - 1) * B;

  __shared__ u16 aT[16][168];
  __shared__ float q[4][16][17];
  __shared__ float redS[8];
  __shared__ float tl[256];

  if (blk < 128) HgfNext[blk * 256 + tid] = 0.0f;

  float tv = 0.0f;
  if (r > 0) {
    tv = t0buf[tid];
    float v = tv;
    #pragma unroll
    for (int off = 1; off < 64; off <<= 1) v = fminf(v, __shfl_xor(v, off));
    if (lane == 0) redS[wave] = v;
  }
  __syncthreads();
  if (r > 0) {
    float mn = fminf(fminf(redS[0], redS[1]), fminf(redS[2], redS[3]));
    if (mn < 0.1f) tv -= mn;
    float v = tv;
    #pragma unroll
    for (int off = 1; off < 64; off <<= 1) v = fmaxf(v, __shfl_xor(v, off));
    if (lane == 0) redS[4 + wave] = v;
  }
  __syncthreads();
  if (r > 0) {
    float mx = fmaxf(fmaxf(redS[4], redS[5]), fmaxf(redS[6], redS[7]));
    if (mx > 1.0f) tv /= mx;
    tv = fminf(fmaxf(tv, tstep[(r - 1) * B + tid]), 1.0f);
    if (blk == 0) {
      tstep[r * B + tid] = tv;
      out[TS_OFF + tid * RW + (r - 1)] = tv;
    }
  }
  tl[tid] = tv;

  {
    const int row = tid >> 4, c8 = (tid & 15) * 8;
    if (r > 0) {
      const float* hp = HgfPrev + (m0 + row) * HIN + c8;
      f32x4 x0 = *(const f32x4*)hp;
      f32x4 x1 = *(const f32x4*)(hp + 4);
      float R = 1.0f / rowLprev[m0 + row];
      aT[row][c8 + 0] = f2bf(x0[0] * R); aT[row][c8 + 1] = f2bf(x0[1] * R);
      aT[row][c8 + 2] = f2bf(x0[2] * R); aT[row][c8 + 3] = f2bf(x0[3] * R);
      aT[row][c8 + 4] = f2bf(x1[0] * R); aT[row][c8 + 5] = f2bf(x1[1] * R);
      aT[row][c8 + 6] = f2bf(x1[2] * R); aT[row][c8 + 7] = f2bf(x1[3] * R);
    } else {
      #pragma unroll
      for (int e = 0; e < 8; ++e) aT[row][c8 + e] = 0;
    }
  }
  __syncthreads();

  for (int i2 = tid; i2 < 512; i2 += 256) {
    int row = i2 >> 5, j = i2 & 31;
    aT[row][128 + j] = (r > 0) ? f2bf(tl[m0 + row] * Wt_up[j] + bt_up[j]) : (u16)0;
  }

  // v-normalize step r-1 (streaming, off critical path; nt store — out never re-read)
  if (r > 0) {
    #pragma unroll
    for (int uu = 0; uu < 8; ++uu) {
      int flat = (blk * 2048 + uu * 256 + tid) * 4;
      int row = flat >> 14;
      float Rv = 1.0f / rowLprev[row];
      u64 ev = *(const u64*)(ebp + flat);
      f32x4 o;
      o[0] = bf2f((u16)ev) * Rv;
      o[1] = bf2f((u16)(ev >> 16)) * Rv;
      o[2] = bf2f((u16)(ev >> 32)) * Rv;
      o[3] = bf2f((u16)(ev >> 48)) * Rv;
      __builtin_nontemporal_store(o,
          (f32x4*)(out + (size_t)row * RWN + (size_t)(r - 1) * N + (flat & (N - 1))));
    }
  }
  __syncthreads();

  // gates GEMM: K = 160 (LDS aT) + 512 (global hprev)
  const int gcol = wave * H + j0 + lr;
  f32x4 acc[2] = {};
  const u16* brow = Wfull + (size_t)gcol * KC2 + 8 * lk;
  const u16* aL   = &aT[lr][8 * lk];
  const u16* arow = hprev + (m0 + lr) * H + 8 * lk;
  mfma_n(acc[0], *(const i32x4*)(aL),       *(const i32x4*)(brow));
  mfma_n(acc[1], *(const i32x4*)(aL + 32),  *(const i32x4*)(brow + 32));
  mfma(acc[0], *(const i32x4*)(aL + 64),  *(const i32x4*)(brow + 64));
  mfma(acc[1], *(const i32x4*)(aL + 96),  *(const i32x4*)(brow + 96));
  mfma(acc[0], *(const i32x4*)(aL + 128), *(const i32x4*)(brow + 128));
  #pragma unroll 4
  for (int i = 5; i < 21; ++i) {
    int kk = i * 32;
    mfma(acc[i & 1], *(const i32x4*)(arow + kk - 160), *(const i32x4*)(brow + kk));
  }
  fence_acc(acc[0]); fence_acc(acc[1]);
  float bias = bcomb[gcol];
  #pragma unroll
  for (int rr = 0; rr < 4; ++rr)
    q[wave][4 * lk + rr][lr] = acc[0][rr] + acc[1][rr] + bias;
  __syncthreads();
  const int r2 = tid >> 4, jj = tid & 15;
  const int b = m0 + r2, j = j0 + jj;
  float gi = q[0][r2][jj], gf = q[1][r2][jj], gg = q[2][r2][jj], go = q[3][r2][jj];
  if (r == 0) {
    const float* gp = g0 + b * 2048 + j;
    gi += gp[0]; gf += gp[512]; gg += gp[1024]; go += gp[1536];
  }
  float c  = cbuf[b * H + j];
  float c2 = sigm(gf) * c + sigm(gi) * tanhf(gg);
  float h2 = sigm(go) * tanhf(c2);
  cbuf[b * H + j] = c2;
  hcur[b * H + j] = f2bf(h2);
}

// ---------- per-step K2: p GEMM -> e bf16 + rowL atomics + Hg atomics + straggler
// grid 1024 = 8 rb(32 rows) x 128 cb(128 cols); wave covers 32 cols.
__global__ __launch_bounds__(256) void k_pgemm2(
    const u16* __restrict__ hb, const u16* __restrict__ Wup,
    const float* __restrict__ b_up, const float* __restrict__ gum,
    u16* __restrict__ eb, float* __restrict__ rowL,
    float* __restrict__ HgfAcc, const u16* __restrict__ Wdn,
    const u16* __restrict__ Wtd, const float* __restrict__ bt_down,
    const float* __restrict__ Wt_pred, const float* __restrict__ du,
    float* __restrict__ t0)
{
  const int rb = blockIdx.x >> 7, cb = blockIdx.x & 127;
  const int wave = threadIdx.x >> 6, lane = threadIdx.x & 63;
  const int lr = lane & 15, lk = lane >> 4;
  const int m0 = rb * 32;
  const int n0 = cb * 128 + wave * 32;

  // prefetch gumbel (nt: read-once stream, keep L2 for weights) + bias early
  float gv[2][4][2], bup0 = b_up[n0 + lr], bup1 = b_up[n0 + 16 + lr];
  #pragma unroll
  for (int mi = 0; mi < 2; ++mi)
    #pragma unroll
    for (int rr = 0; rr < 4; ++rr) {
      int row = m0 + 16 * mi + 4 * lk + rr;
      gv[mi][rr][0] = __builtin_nontemporal_load(gum + (size_t)row * N + n0 + lr);
      gv[mi][rr][1] = __builtin_nontemporal_load(gum + (size_t)row * N + n0 + 16 + lr);
    }

  f32x4 acc[2][2] = {};
  const u16* a0 = hb + (m0 + lr) * H + 8 * lk;
  const u16* a1 = a0 + 16 * H;
  const u16* b0 = Wup + (size_t)(n0 + lr) * H + 8 * lk;
  const u16* b1 = b0 + 16 * H;
  {
    i32x4 af0 = *(const i32x4*)(a0);
    i32x4 af1 = *(const i32x4*)(a1);
    i32x4 bf0 = *(const i32x4*)(b0);
    i32x4 bf1 = *(const i32x4*)(b1);
    mfma_n(acc[0][0], af0, bf0); mfma_n(acc[0][1], af0, bf1);
    mfma_n(acc[1][0], af1, bf0); mfma_n(acc[1][1], af1, bf1);
  }
  #pragma unroll 3
  for (int kk = 32; kk < H; kk += 32) {
    i32x4 af0 = *(const i32x4*)(a0 + kk);
    i32x4 af1 = *(const i32x4*)(a1 + kk);
    i32x4 bf0 = *(const i32x4*)(b0 + kk);
    i32x4 bf1 = *(const i32x4*)(b1 + kk);
    mfma(acc[0][0], af0, bf0); mfma(acc[0][1], af0, bf1);
    mfma(acc[1][0], af1, bf0); mfma(acc[1][1], af1, bf1);
  }
  #pragma unroll
  for (int mi = 0; mi < 2; ++mi) { fence_acc(acc[mi][0]); fence_acc(acc[mi][1]); }

  __shared__ u16 eLb[32][136];
  __shared__ float sL[4][32];
  #pragma unroll
  for (int mi = 0; mi < 2; ++mi)
    #pragma unroll
    for (int rr = 0; rr < 4; ++rr) {
      int rl = 16 * mi + 4 * lk + rr;
      int row = m0 + rl;
      u16* sp = eb + (size_t)row * N + n0 + lr;
      float v0 = acc[mi][0][rr] + bup0 + gv[mi][rr][0];
      float v1 = acc[mi][1][rr] + bup1 + gv[mi][rr][1];
      float e0 = expf(fminf(v0, 80.0f));
      float e1 = expf(fminf(v1, 80.0f));
      u16 p0 = f2bf(e0), p1 = f2bf(e1);
      sp[0] = p0; sp[16] = p1;
      eLb[rl][wave * 32 + lr] = p0;
      eLb[rl][wave * 32 + 16 + lr] = p1;
      float par = e0 + e1;
      #pragma unroll
      for (int off = 1; off < 16; off <<= 1) par += __shfl_xor(par, off);
      if (lr == 0) sL[wave][rl] = par;
    }
  __syncthreads();
  if (threadIdx.x < 32)
    atomicAdd(rowL + m0 + threadIdx.x,
              sL[0][threadIdx.x] + sL[1][threadIdx.x] + sL[2][threadIdx.x] + sL[3][threadIdx.x]);

  // Hg partial GEMM over this block's K-slab -> f32 atomics into HgfAcc (L2-resident)
  const int nb = cb * 128;
  f32x4 acc2[2][2] = {};
  #pragma unroll
  for (int kk2 = 0; kk2 < 4; ++kk2) {
    i32x4 af0 = *(const i32x4*)(&eLb[lr][kk2 * 32 + 8 * lk]);
    i32x4 af1 = *(const i32x4*)(&eLb[16 + lr][kk2 * 32 + 8 * lk]);
    i32x4 bf0 = *(const i32x4*)(Wdn + (size_t)(wave * 32 + lr) * N + nb + kk2 * 32 + 8 * lk);
    i32x4 bf1 = *(const i32x4*)(Wdn + (size_t)(wave * 32 + 16 + lr) * N + nb + kk2 * 32 + 8 * lk);
    mfma(acc2[0][0], af0, bf0); mfma(acc2[0][1], af0, bf1);
    mfma(acc2[1][0], af1, bf0); mfma(acc2[1][1], af1, bf1);
  }
  #pragma unroll
  for (int mi2 = 0; mi2 < 2; ++mi2) { fence_acc(acc2[mi2][0]); fence_acc(acc2[mi2][1]); }
  #pragma unroll
  for (int mi2 = 0; mi2 < 2; ++mi2)
    #pragma unroll
    for (int ni = 0; ni < 2; ++ni)
      #pragma unroll
      for (int rr = 0; rr < 4; ++rr)
        atomicAdd(HgfAcc + (m0 + 16 * mi2 + 4 * lk + rr) * HIN + wave * 32 + 16 * ni + lr,
                  acc2[mi2][ni][rr]);

  // straggler: td = tanh(h2 @ Wt_down^T + bt)*mask/keep ; t0 = min(td @ Wt_pred^T, 1)
  if (cb == 0 && wave < 2) {
    f32x4 acc3[2] = {};
    const u16* at = hb + (m0 + wave * 16 + lr) * H + 8 * lk;
    {
      i32x4 af = *(const i32x4*)(at);
      mfma_n(acc3[0], af, *(const i32x4*)(Wtd + lr * H + 8 * lk));
      mfma_n(acc3[1], af, *(const i32x4*)(Wtd + (16 + lr) * H + 8 * lk));
    }
    for (int kk = 32; kk < H; kk += 32) {
      i32x4 af = *(const i32x4*)(at + kk);
      mfma(acc3[0], af, *(const i32x4*)(Wtd + lr * H + kk + 8 * lk));
      mfma(acc3[1], af, *(const i32x4*)(Wtd + (16 + lr) * H + kk + 8 * lk));
    }
    fence_acc(acc3[0]); fence_acc(acc3[1]);
    float wp0 = Wt_pred[lr],  wp1 = Wt_pred[16 + lr];
    float bt0 = bt_down[lr],  bt1 = bt_down[16 + lr];
    #pragma unroll
    for (int rr = 0; rr < 4; ++rr) {
      int row = m0 + wave * 16 + 4 * lk + rr;
      float td0 = tanhf(acc3[0][rr] + bt0);
      float td1 = tanhf(acc3[1][rr] + bt1);
      td0 = (du[row * HT + lr]      < 0.8f) ? td0 * 1.25f : 0.0f;
      td1 = (du[row * HT + 16 + lr] < 0.8f) ? td1 * 1.25f : 0.0f;
      float part = td0 * wp0 + td1 * wp1;
      #pragma unroll
      for (int off = 1; off < 16; off <<= 1) part += __shfl_xor(part, off);
      if (lr == 0) t0[row] = fminf(part, 1.0f);
    }
  }
}

// ---------- tail: normalize step 15 + t15 finish ----------
__global__ __launch_bounds__(256) void k_tail(
    float* __restrict__ out, const u16* __restrict__ eb15,
    const float* __restrict__ rowLs, const float* __restrict__ t0buf,
    float* __restrict__ tstep)
{
  const int blk = blockIdx.x, tid = threadIdx.x;
  const float* rowL15 = rowLs + 15 * B;
  #pragma unroll
  for (int uu = 0; uu < 4; ++uu) {
    int flat = (blk * 1024 + uu * 256 + tid) * 4;
    int row = flat >> 14;
    float Rv = 1.0f / rowL15[row];
    u64 ev = *(const u64*)(eb15 + flat);
    f32x4 o;
    o[0] = bf2f((u16)ev) * Rv;
    o[1] = bf2f((u16)(ev >> 16)) * Rv;
    o[2] = bf2f((u16)(ev >> 32)) * Rv;
    o[3] = bf2f((u16)(ev >> 48)) * Rv;
    __builtin_nontemporal_store(o,
        (f32x4*)(out + (size_t)row * RWN + (size_t)15 * N + (flat & (N - 1))));
  }
  if (blk == 0) {
    const int wave = tid >> 6, lane = tid & 63;
    __shared__ float redS[8];
    float tv = t0buf[tid];
    float v = tv;
    #pragma unroll
    for (int off = 1; off < 64; off <<= 1) v = fminf(v, __shfl_xor(v, off));
    if (lane == 0) redS[wave] = v;
    __syncthreads();
    float mn = fminf(fminf(redS[0], redS[1]), fminf(redS[2], redS[3]));
    if (mn < 0.1f) tv -= mn;
    v = tv;
    #pragma unroll
    for (int off = 1; off < 64; off <<= 1) v = fmaxf(v, __shfl_xor(v, off));
    if (lane == 0) redS[4 + wave] = v;
    __syncthreads();
    float mx = fmaxf(fmaxf(redS[4], redS[5]), fmaxf(redS[6], redS[7]));
    if (mx > 1.0f) tv /= mx;
    tv = fminf(fmaxf(tv, tstep[15 * B + tid]), 1.0f);
    tstep[16 * B + tid] = tv;
    out[TS_OFF + tid * RW + 15] = tv;
  }
}

__global__ __launch_bounds__(256) void k_prob(
    const float* __restrict__ Hgf15, const float* __restrict__ rowLs,
    const float* __restrict__ tstep, const float* __restrict__ Wt_up,
    const float* __restrict__ bt_up, const float* __restrict__ wpc,
    float* __restrict__ outp)
{
  int b = threadIdx.x;
  float R = 1.0f / rowLs[15 * B + b];
  float acc = 0.0f;
  for (int m = 0; m < HIN; ++m) acc += Hgf15[b * HIN + m] * R * wpc[m];
  float tv = tstep[16 * B + b];
  for (int j = 0; j < HT; ++j) acc += (tv * Wt_up[j] + bt_up[j]) * wpc[HIN + j];
  outp[b] = acc;
}

// ---------- launch ----------
extern "C" void kernel_launch(void* const* d_in, const int* in_sizes, int n_in,
                              void* d_out, int out_size, void* d_ws, size_t ws_size,
                              hipStream_t stream) {
  (void)in_sizes; (void)n_in; (void)out_size; (void)ws_size;
  const float* latent  = (const float*)d_in[0];
  const float* inputs0 = (const float*)d_in[1];
  const float* Wc      = (const float*)d_in[2];
  const float* bc      = (const float*)d_in[3];
  const float* Ws      = (const float*)d_in[4];
  const float* bs      = (const float*)d_in[5];
  const float* Wh      = (const float*)d_in[6];
  const float* bh      = (const float*)d_in[7];
  const float* Wcc     = (const float*)d_in[8];
  const float* bcc     = (const float*)d_in[9];
  const float* W_ih    = (const float*)d_in[10];
  const float* b_ih    = (const float*)d_in[11];
  const float* W_hh    = (const float*)d_in[12];
  const float* b_hh    = (const float*)d_in[13];
  const float* W_up    = (const float*)d_in[14];
  const float* b_up    = (const float*)d_in[15];
  const float* W_down  = (const float*)d_in[16];
  const float* Wt_down = (const float*)d_in[17];
  const float* bt_down = (const float*)d_in[18];
  const float* Wt_pred = (const float*)d_in[19];
  const float* Wt_up   = (const float*)d_in[20];
  const float* bt_up   = (const float*)d_in[21];
  const float* W_vt    = (const float*)d_in[22];
  const float* W_prob  = (const float*)d_in[23];
  const float* gumbel  = (const float*)d_in[24];
  const float* drop_u  = (const float*)d_in[25];
  float* out = (float*)d_out;

  char* p = (char*)d_ws;
  auto alloc = [&](size_t bytes) { char* r = p; p += (bytes + 255) & ~(size_t)255; return r; };
  u16*   Wup_b  = (u16*)  alloc((size_t)N * H * 2);
  u16*   Wdn_b  = (u16*)  alloc((size_t)HIN * N * 2);
  u16*   Wfull_b= (u16*)  alloc((size_t)4 * H * KC2 * 2);
  u16*   Wtd_b  = (u16*)  alloc((size_t)HT * H * 2);
  u16*   Whc_b  = (u16*)  alloc((size_t)2 * H * H * 2);
  float* bcomb  = (float*)alloc(4 * H * 4);
  u16*   hbuf0  = (u16*)  alloc((size_t)B * H * 2);
  u16*   hbuf1  = (u16*)  alloc((size_t)B * H * 2);
  float* cbuf   = (float*)alloc((size_t)B * H * 4);
  u16*   sinit_b= (u16*)  alloc((size_t)B * H * 2);
  float* latbuf = (float*)alloc((size_t)B * HIN * 4);
  float* rowLs  = (float*)alloc((size_t)16 * B * 4);
  float* t0buf  = (float*)alloc(B * 4);
  float* tstep  = (float*)alloc((size_t)17 * B * 4);
  float* Hgf2_0 = (float*)alloc((size_t)B * HIN * 4);
  float* Hgf2_1 = (float*)alloc((size_t)B * HIN * 4);
  float* g0add  = (float*)alloc((size_t)B * 4 * H * 4);
  float* wpc    = (float*)alloc(160 * 4);
  u16*   ebuf0  = (u16*)  alloc((size_t)B * N * 2);
  u16*   ebuf1  = (u16*)  alloc((size_t)B * N * 2);

  k_prep<<<2048, 256, 0, stream>>>(W_up, W_down, W_hh, Wt_down, b_ih, b_hh, Wh, Wcc,
                                   Wup_b, Wdn_b, Wfull_b, Wtd_b, Whc_b, bcomb,
                                   tstep, rowLs);
  k_fold<<<3330, 256, 0, stream>>>(W_ih, W_vt, inputs0, W_prob, Wfull_b, g0add, wpc);
  k_lat  <<<128, 256, 0, stream>>>(latent, Wc, bc, latbuf);
  k_sinit<<<512, 256, 0, stream>>>(latbuf, Ws, bs, sinit_b);
  k_h0c0m<<<1024, 256, 0, stream>>>(sinit_b, Whc_b, bh, bcc, cbuf, hbuf1);

  for (int r = 0; r < 16; ++r) {
    u16* hprev = (r & 1) ? hbuf0 : hbuf1;
    u16* hcur  = (r & 1) ? hbuf1 : hbuf0;
    u16* eb    = (r & 1) ? ebuf1 : ebuf0;
    u16* ebp   = (r & 1) ? ebuf0 : ebuf1;
    float* HgfCur  = (r & 1) ? Hgf2_1 : Hgf2_0;
    float* HgfPrev = (r & 1) ? Hgf2_0 : Hgf2_1;
    k_lstm2<<<512, 256, 0, stream>>>(hprev, hcur, Wfull_b, bcomb, cbuf, g0add,
                                     HgfPrev, HgfCur, rowLs, t0buf, tstep,
                                     Wt_up, bt_up, out, ebp, r);
    k_pgemm2<<<1024, 256, 0, stream>>>(hcur, Wup_b, b_up, gumbel + (size_t)r * B * N,
                                       eb, rowLs + r * B, HgfCur, Wdn_b,
                                       Wtd_b, bt_down, Wt_pred,
                                       drop_u + (size_t)r * B * HT, t0buf);
  }
  k_tail<<<1024, 256, 0, stream>>>(out, ebuf1, rowLs, t0buf, tstep);
  k_prob<<<1, 256, 0, stream>>>(Hgf2_1, rowLs, tstep, Wt_up, bt_up, wpc, out + PROB_OFF);
}

// Round 18
// 1166.490 us; speedup vs baseline: 1.0559x; 1.0071x over previous
//
#include <hip/hip_runtime.h>

typedef float  __attribute__((ext_vector_type(4))) f32x4;
typedef int    __attribute__((ext_vector_type(4))) i32x4;
typedef unsigned short u16;
typedef unsigned long long u64;

#define B    256
#define H    512
#define HIN  128
#define N    16384
#define RW   16
#define HT   32
#define KC2  672          // 160 (Hg|Ht) + 512 (h) — Wfull K
#define RWN  262144       // RW*N
#define TS_OFF   67108864 // B*RW*N
#define PROB_OFF 67112960 // TS_OFF + B*RW

// ---------- helpers ----------
__device__ __forceinline__ u16 f2bf(float f) {
  unsigned u = __builtin_bit_cast(unsigned, f);
  u += 0x7FFFu + ((u >> 16) & 1u);         // RTNE
  return (u16)(u >> 16);
}
__device__ __forceinline__ float bf2f(u16 v) {
  return __builtin_bit_cast(float, ((unsigned)v) << 16);
}
__device__ __forceinline__ float sigm(float x) { return 1.0f / (1.0f + expf(-x)); }

// NON-volatile asm: "+v" data deps keep ordering & liveness; scheduler may now
// hoist loads across MFMAs and software-pipeline the K-loop.
__device__ __forceinline__ void mfma(f32x4& d, i32x4 a, i32x4 b) {
  asm("v_mfma_f32_16x16x32_bf16 %0, %1, %2, %0" : "+v"(d) : "v"(a), "v"(b));
}
// s_nop stays INSIDE the asm so it remains glued to its MFMA under scheduling.
__device__ __forceinline__ void mfma_n(f32x4& d, i32x4 a, i32x4 b) {
  asm("s_nop 1\n\tv_mfma_f32_16x16x32_bf16 %0, %1, %2, %0" : "+v"(d) : "v"(a), "v"(b));
}
__device__ __forceinline__ void fence_acc(f32x4& v) {
  asm("s_nop 7\n\ts_nop 7" : "+v"(v));
}

// ---------- prologue ----------
__global__ __launch_bounds__(256) void k_prep(
    const float* __restrict__ W_up, const float* __restrict__ W_down,
    const float* __restrict__ W_hh, const float* __restrict__ Wt_down,
    const float* __restrict__ b_ih, const float* __restrict__ b_hh,
    const float* __restrict__ Wh, const float* __restrict__ Wcc,
    u16* __restrict__ Wup_b, u16* __restrict__ Wdn_b, u16* __restrict__ Wfull,
    u16* __restrict__ Wtd_b, u16* __restrict__ Whc_b,
    float* __restrict__ bcomb, float* __restrict__ tstep, float* __restrict__ rowLs)
{
  const int idx0 = blockIdx.x * 256 + threadIdx.x;
  const int stride = gridDim.x * 256;
  for (int i = idx0; i < N * H; i += stride) Wup_b[i] = f2bf(W_up[i]);
  for (int i = idx0; i < HIN * N; i += stride) Wdn_b[i] = f2bf(W_down[i]);
  for (int i = idx0; i < 4 * H * H; i += stride) {
    int j = i >> 9, k = i & 511;
    Wfull[j * KC2 + 160 + k] = f2bf(W_hh[i]);
  }
  for (int i = idx0; i < HT * H; i += stride) Wtd_b[i] = f2bf(Wt_down[i]);
  for (int i = idx0; i < 2 * H * H; i += stride) {
    int j = i >> 9, k = i & 511;
    Whc_b[i] = f2bf(j < H ? Wh[j * H + k] : Wcc[(j - H) * H + k]);
  }
  for (int i = idx0; i < 4 * H; i += stride) bcomb[i] = b_ih[i] + b_hh[i];
  for (int i = idx0; i < B; i += stride) tstep[i] = 0.0f;
  for (int i = idx0; i < 16 * B; i += stride) rowLs[i] = 0.0f;
}

// Wcomb = W_ih @ W_vt into Wfull cols 0..159; g0add = inputs0 @ W_ih^T; wpc = W_prob @ W_vt
__global__ __launch_bounds__(256) void k_fold(
    const float* __restrict__ W_ih, const float* __restrict__ W_vt,
    const float* __restrict__ inputs0, const float* __restrict__ W_prob,
    u16* __restrict__ Wfull, float* __restrict__ g0add, float* __restrict__ wpc)
{
  int idx = blockIdx.x * 256 + threadIdx.x;
  if (idx < 2048 * 160) {
    int j = idx / 160, m = idx - j * 160;
    float a = 0.0f;
    for (int c = 0; c < HIN; ++c) a += W_ih[j * HIN + c] * W_vt[c * 160 + m];
    Wfull[j * KC2 + m] = f2bf(a);
  } else if (idx < 2048 * 160 + 256 * 2048) {
    int i2 = idx - 2048 * 160;
    int b = i2 >> 11, j = i2 & 2047;
    float a = 0.0f;
    for (int k = 0; k < HIN; ++k) a += inputs0[b * HIN + k] * W_ih[j * HIN + k];
    g0add[i2] = a;
  } else if (idx < 2048 * 160 + 256 * 2048 + 160) {
    int m = idx - (2048 * 160 + 256 * 2048);
    float a = 0.0f;
    for (int k = 0; k < HIN; ++k) a += W_prob[k] * W_vt[k * 160 + m];
    wpc[m] = a;
  }
}

__global__ __launch_bounds__(256) void k_lat(
    const float* __restrict__ latent, const float* __restrict__ Wc,
    const float* __restrict__ bc, float* __restrict__ latbuf)
{
  int idx = blockIdx.x * 256 + threadIdx.x;
  int b = idx >> 7, i = idx & 127;
  float acc = bc[i];
  for (int k = 0; k < 129; ++k) acc += latent[b * 129 + k] * Wc[i * 129 + k];
  latbuf[idx] = tanhf(acc);
}

__global__ __launch_bounds__(256) void k_sinit(
    const float* __restrict__ latbuf, const float* __restrict__ Ws,
    const float* __restrict__ bs, u16* __restrict__ sinit_b)
{
  int idx = blockIdx.x * 256 + threadIdx.x;
  int b = idx >> 9, j = idx & 511;
  float acc = bs[j];
  for (int k = 0; k < HIN; ++k) acc += latbuf[b * HIN + k] * Ws[j * HIN + k];
  sinit_b[idx] = f2bf(tanhf(acc));
}

// h0/c0 via MFMA: h0 -> hbuf1 [256][512] bf16, c0 -> cbuf f32
__global__ __launch_bounds__(256) void k_h0c0m(
    const u16* __restrict__ sinit_b, const u16* __restrict__ Whc_b,
    const float* __restrict__ bh, const float* __restrict__ bcc,
    float* __restrict__ cbuf, u16* __restrict__ h0out)
{
  const int rb = blockIdx.x >> 6, cb = blockIdx.x & 63;
  const int wave = threadIdx.x >> 6, lane = threadIdx.x & 63;
  const int lr = lane & 15, lk = lane >> 4;
  const int m0 = rb * 16, col0 = cb * 16;
  const u16* ab = sinit_b + (m0 + lr) * H + wave * 128 + 8 * lk;
  const u16* bb = Whc_b + (col0 + lr) * H + wave * 128 + 8 * lk;
  f32x4 acc[2] = {};
  mfma_n(acc[0], *(const i32x4*)(ab),      *(const i32x4*)(bb));
  mfma_n(acc[1], *(const i32x4*)(ab + 32), *(const i32x4*)(bb + 32));
  mfma(acc[0], *(const i32x4*)(ab + 64), *(const i32x4*)(bb + 64));
  mfma(acc[1], *(const i32x4*)(ab + 96), *(const i32x4*)(bb + 96));
  fence_acc(acc[0]); fence_acc(acc[1]);
  __shared__ float q[4][16][17];
  #pragma unroll
  for (int rr = 0; rr < 4; ++rr)
    q[wave][4 * lk + rr][lr] = acc[0][rr] + acc[1][rr];
  __syncthreads();
  const int r2 = threadIdx.x >> 4, jj = threadIdx.x & 15;
  float s = q[0][r2][jj] + q[1][r2][jj] + q[2][r2][jj] + q[3][r2][jj];
  int col = col0 + jj;
  if (col < H) h0out[(m0 + r2) * H + col] = f2bf(tanhf(s + bh[col]));
  else         cbuf[(m0 + r2) * H + col - H] = tanhf(s + bcc[col - H]);
}

// ---------- per-step K1: finish step r-1 (t-constraint, Hgf read+scale, v-normalize)
//            + gates GEMM (A = [Hg|Ht] from LDS, h from global) + LSTM pointwise
__global__ __launch_bounds__(256) void k_lstm2(
    const u16* __restrict__ hprev, u16* __restrict__ hcur,
    const u16* __restrict__ Wfull, const float* __restrict__ bcomb,
    float* __restrict__ cbuf, const float* __restrict__ g0,
    const float* __restrict__ HgfPrev, float* __restrict__ HgfNext,
    const float* __restrict__ rowLs, const float* __restrict__ t0buf,
    float* __restrict__ tstep, const float* __restrict__ Wt_up,
    const float* __restrict__ bt_up, float* __restrict__ out,
    const u16* __restrict__ ebp, int r)
{
  const int blk = blockIdx.x, tid = threadIdx.x;
  const int wave = tid >> 6, lane = tid & 63;
  const int lr = lane & 15, lk = lane >> 4;
  const int rb = blk & 15, cb = blk >> 4;
  const int m0 = rb * 16, j0 = cb * 16;
  const float* rowLprev = rowLs + (r - 1) * B;

  __shared__ u16 aT[16][168];
  __shared__ float q[4][16][17];
  __shared__ float redS[8];
  __shared__ float tl[256];

  if (blk < 128) HgfNext[blk * 256 + tid] = 0.0f;

  float tv = 0.0f;
  if (r > 0) {
    tv = t0buf[tid];
    float v = tv;
    #pragma unroll
    for (int off = 1; off < 64; off <<= 1) v = fminf(v, __shfl_xor(v, off));
    if (lane == 0) redS[wave] = v;
  }
  __syncthreads();
  if (r > 0) {
    float mn = fminf(fminf(redS[0], redS[1]), fminf(redS[2], redS[3]));
    if (mn < 0.1f) tv -= mn;
    float v = tv;
    #pragma unroll
    for (int off = 1; off < 64; off <<= 1) v = fmaxf(v, __shfl_xor(v, off));
    if (lane == 0) redS[4 + wave] = v;
  }
  __syncthreads();
  if (r > 0) {
    float mx = fmaxf(fmaxf(redS[4], redS[5]), fmaxf(redS[6], redS[7]));
    if (mx > 1.0f) tv /= mx;
    tv = fminf(fmaxf(tv, tstep[(r - 1) * B + tid]), 1.0f);
    if (blk == 0) {
      tstep[r * B + tid] = tv;
      out[TS_OFF + tid * RW + (r - 1)] = tv;
    }
  }
  tl[tid] = tv;

  {
    const int row = tid >> 4, c8 = (tid & 15) * 8;
    if (r > 0) {
      const float* hp = HgfPrev + (m0 + row) * HIN + c8;
      f32x4 x0 = *(const f32x4*)hp;
      f32x4 x1 = *(const f32x4*)(hp + 4);
      float R = 1.0f / rowLprev[m0 + row];
      aT[row][c8 + 0] = f2bf(x0[0] * R); aT[row][c8 + 1] = f2bf(x0[1] * R);
      aT[row][c8 + 2] = f2bf(x0[2] * R); aT[row][c8 + 3] = f2bf(x0[3] * R);
      aT[row][c8 + 4] = f2bf(x1[0] * R); aT[row][c8 + 5] = f2bf(x1[1] * R);
      aT[row][c8 + 6] = f2bf(x1[2] * R); aT[row][c8 + 7] = f2bf(x1[3] * R);
    } else {
      #pragma unroll
      for (int e = 0; e < 8; ++e) aT[row][c8 + e] = 0;
    }
  }
  __syncthreads();

  for (int i2 = tid; i2 < 512; i2 += 256) {
    int row = i2 >> 5, j = i2 & 31;
    aT[row][128 + j] = (r > 0) ? f2bf(tl[m0 + row] * Wt_up[j] + bt_up[j]) : (u16)0;
  }

  // v-normalize step r-1 (streaming, off critical path)
  if (r > 0) {
    #pragma unroll
    for (int uu = 0; uu < 8; ++uu) {
      int flat = (blk * 2048 + uu * 256 + tid) * 4;
      int row = flat >> 14;
      float Rv = 1.0f / rowLprev[row];
      u64 ev = *(const u64*)(ebp + flat);
      f32x4 o;
      o[0] = bf2f((u16)ev) * Rv;
      o[1] = bf2f((u16)(ev >> 16)) * Rv;
      o[2] = bf2f((u16)(ev >> 32)) * Rv;
      o[3] = bf2f((u16)(ev >> 48)) * Rv;
      *(f32x4*)(out + (size_t)row * RWN + (size_t)(r - 1) * N + (flat & (N - 1))) = o;
    }
  }
  __syncthreads();

  // gates GEMM: K = 160 (LDS aT) + 512 (global hprev)
  const int gcol = wave * H + j0 + lr;
  f32x4 acc[2] = {};
  const u16* brow = Wfull + (size_t)gcol * KC2 + 8 * lk;
  const u16* aL   = &aT[lr][8 * lk];
  const u16* arow = hprev + (m0 + lr) * H + 8 * lk;
  mfma_n(acc[0], *(const i32x4*)(aL),       *(const i32x4*)(brow));
  mfma_n(acc[1], *(const i32x4*)(aL + 32),  *(const i32x4*)(brow + 32));
  mfma(acc[0], *(const i32x4*)(aL + 64),  *(const i32x4*)(brow + 64));
  mfma(acc[1], *(const i32x4*)(aL + 96),  *(const i32x4*)(brow + 96));
  mfma(acc[0], *(const i32x4*)(aL + 128), *(const i32x4*)(brow + 128));
  #pragma unroll 4
  for (int i = 5; i < 21; ++i) {
    int kk = i * 32;
    mfma(acc[i & 1], *(const i32x4*)(arow + kk - 160), *(const i32x4*)(brow + kk));
  }
  fence_acc(acc[0]); fence_acc(acc[1]);
  float bias = bcomb[gcol];
  #pragma unroll
  for (int rr = 0; rr < 4; ++rr)
    q[wave][4 * lk + rr][lr] = acc[0][rr] + acc[1][rr] + bias;
  __syncthreads();
  const int r2 = tid >> 4, jj = tid & 15;
  const int b = m0 + r2, j = j0 + jj;
  float gi = q[0][r2][jj], gf = q[1][r2][jj], gg = q[2][r2][jj], go = q[3][r2][jj];
  if (r == 0) {
    const float* gp = g0 + b * 2048 + j;
    gi += gp[0]; gf += gp[512]; gg += gp[1024]; go += gp[1536];
  }
  float c  = cbuf[b * H + j];
  float c2 = sigm(gf) * c + sigm(gi) * tanhf(gg);
  float h2 = sigm(go) * tanhf(c2);
  cbuf[b * H + j] = c2;
  hcur[b * H + j] = f2bf(h2);
}

// ---------- per-step K2: p GEMM -> e bf16 + rowL atomics + Hg atomics + straggler
// grid 1024 = 8 rb(32 rows) x 128 cb(128 cols); wave covers 32 cols.
__global__ __launch_bounds__(256) void k_pgemm2(
    const u16* __restrict__ hb, const u16* __restrict__ Wup,
    const float* __restrict__ b_up, const float* __restrict__ gum,
    u16* __restrict__ eb, float* __restrict__ rowL,
    float* __restrict__ HgfAcc, const u16* __restrict__ Wdn,
    const u16* __restrict__ Wtd, const float* __restrict__ bt_down,
    const float* __restrict__ Wt_pred, const float* __restrict__ du,
    float* __restrict__ t0)
{
  const int rb = blockIdx.x >> 7, cb = blockIdx.x & 127;
  const int wave = threadIdx.x >> 6, lane = threadIdx.x & 63;
  const int lr = lane & 15, lk = lane >> 4;
  const int m0 = rb * 32;
  const int n0 = cb * 128 + wave * 32;

  // prefetch gumbel + bias early: HBM latency hides under the K-loop MFMAs
  float gv[2][4][2], bup0 = b_up[n0 + lr], bup1 = b_up[n0 + 16 + lr];
  #pragma unroll
  for (int mi = 0; mi < 2; ++mi)
    #pragma unroll
    for (int rr = 0; rr < 4; ++rr) {
      int row = m0 + 16 * mi + 4 * lk + rr;
      gv[mi][rr][0] = gum[(size_t)row * N + n0 + lr];
      gv[mi][rr][1] = gum[(size_t)row * N + n0 + 16 + lr];
    }

  f32x4 acc[2][2] = {};
  const u16* a0 = hb + (m0 + lr) * H + 8 * lk;
  const u16* a1 = a0 + 16 * H;
  const u16* b0 = Wup + (size_t)(n0 + lr) * H + 8 * lk;
  const u16* b1 = b0 + 16 * H;
  {
    i32x4 af0 = *(const i32x4*)(a0);
    i32x4 af1 = *(const i32x4*)(a1);
    i32x4 bf0 = *(const i32x4*)(b0);
    i32x4 bf1 = *(const i32x4*)(b1);
    mfma_n(acc[0][0], af0, bf0); mfma_n(acc[0][1], af0, bf1);
    mfma_n(acc[1][0], af1, bf0); mfma_n(acc[1][1], af1, bf1);
  }
  #pragma unroll 3
  for (int kk = 32; kk < H; kk += 32) {
    i32x4 af0 = *(const i32x4*)(a0 + kk);
    i32x4 af1 = *(const i32x4*)(a1 + kk);
    i32x4 bf0 = *(const i32x4*)(b0 + kk);
    i32x4 bf1 = *(const i32x4*)(b1 + kk);
    mfma(acc[0][0], af0, bf0); mfma(acc[0][1], af0, bf1);
    mfma(acc[1][0], af1, bf0); mfma(acc[1][1], af1, bf1);
  }
  #pragma unroll
  for (int mi = 0; mi < 2; ++mi) { fence_acc(acc[mi][0]); fence_acc(acc[mi][1]); }

  __shared__ u16 eLb[32][136];
  __shared__ float sL[4][32];
  #pragma unroll
  for (int mi = 0; mi < 2; ++mi)
    #pragma unroll
    for (int rr = 0; rr < 4; ++rr) {
      int rl = 16 * mi + 4 * lk + rr;
      int row = m0 + rl;
      u16* sp = eb + (size_t)row * N + n0 + lr;
      float v0 = acc[mi][0][rr] + bup0 + gv[mi][rr][0];
      float v1 = acc[mi][1][rr] + bup1 + gv[mi][rr][1];
      float e0 = expf(fminf(v0, 80.0f));
      float e1 = expf(fminf(v1, 80.0f));
      u16 p0 = f2bf(e0), p1 = f2bf(e1);
      sp[0] = p0; sp[16] = p1;
      eLb[rl][wave * 32 + lr] = p0;
      eLb[rl][wave * 32 + 16 + lr] = p1;
      float par = e0 + e1;
      #pragma unroll
      for (int off = 1; off < 16; off <<= 1) par += __shfl_xor(par, off);
      if (lr == 0) sL[wave][rl] = par;
    }
  __syncthreads();
  if (threadIdx.x < 32)
    atomicAdd(rowL + m0 + threadIdx.x,
              sL[0][threadIdx.x] + sL[1][threadIdx.x] + sL[2][threadIdx.x] + sL[3][threadIdx.x]);

  // Hg partial GEMM over this block's K-slab -> f32 atomics into HgfAcc (L2-resident)
  const int nb = cb * 128;
  f32x4 acc2[2][2] = {};
  #pragma unroll
  for (int kk2 = 0; kk2 < 4; ++kk2) {
    i32x4 af0 = *(const i32x4*)(&eLb[lr][kk2 * 32 + 8 * lk]);
    i32x4 af1 = *(const i32x4*)(&eLb[16 + lr][kk2 * 32 + 8 * lk]);
    i32x4 bf0 = *(const i32x4*)(Wdn + (size_t)(wave * 32 + lr) * N + nb + kk2 * 32 + 8 * lk);
    i32x4 bf1 = *(const i32x4*)(Wdn + (size_t)(wave * 32 + 16 + lr) * N + nb + kk2 * 32 + 8 * lk);
    mfma(acc2[0][0], af0, bf0); mfma(acc2[0][1], af0, bf1);
    mfma(acc2[1][0], af1, bf0); mfma(acc2[1][1], af1, bf1);
  }
  #pragma unroll
  for (int mi2 = 0; mi2 < 2; ++mi2) { fence_acc(acc2[mi2][0]); fence_acc(acc2[mi2][1]); }
  #pragma unroll
  for (int mi2 = 0; mi2 < 2; ++mi2)
    #pragma unroll
    for (int ni = 0; ni < 2; ++ni)
      #pragma unroll
      for (int rr = 0; rr < 4; ++rr)
        atomicAdd(HgfAcc + (m0 + 16 * mi2 + 4 * lk + rr) * HIN + wave * 32 + 16 * ni + lr,
                  acc2[mi2][ni][rr]);

  // straggler: td = tanh(h2 @ Wt_down^T + bt)*mask/keep ; t0 = min(td @ Wt_pred^T, 1)
  if (cb == 0 && wave < 2) {
    f32x4 acc3[2] = {};
    const u16* at = hb + (m0 + wave * 16 + lr) * H + 8 * lk;
    {
      i32x4 af = *(const i32x4*)(at);
      mfma_n(acc3[0], af, *(const i32x4*)(Wtd + lr * H + 8 * lk));
      mfma_n(acc3[1], af, *(const i32x4*)(Wtd + (16 + lr) * H + 8 * lk));
    }
    for (int kk = 32; kk < H; kk += 32) {
      i32x4 af = *(const i32x4*)(at + kk);
      mfma(acc3[0], af, *(const i32x4*)(Wtd + lr * H + kk + 8 * lk));
      mfma(acc3[1], af, *(const i32x4*)(Wtd + (16 + lr) * H + kk + 8 * lk));
    }
    fence_acc(acc3[0]); fence_acc(acc3[1]);
    float wp0 = Wt_pred[lr],  wp1 = Wt_pred[16 + lr];
    float bt0 = bt_down[lr],  bt1 = bt_down[16 + lr];
    #pragma unroll
    for (int rr = 0; rr < 4; ++rr) {
      int row = m0 + wave * 16 + 4 * lk + rr;
      float td0 = tanhf(acc3[0][rr] + bt0);
      float td1 = tanhf(acc3[1][rr] + bt1);
      td0 = (du[row * HT + lr]      < 0.8f) ? td0 * 1.25f : 0.0f;
      td1 = (du[row * HT + 16 + lr] < 0.8f) ? td1 * 1.25f : 0.0f;
      float part = td0 * wp0 + td1 * wp1;
      #pragma unroll
      for (int off = 1; off < 16; off <<= 1) part += __shfl_xor(part, off);
      if (lr == 0) t0[row] = fminf(part, 1.0f);
    }
  }
}

// ---------- tail: normalize step 15 + t15 finish ----------
__global__ __launch_bounds__(256) void k_tail(
    float* __restrict__ out, const u16* __restrict__ eb15,
    const float* __restrict__ rowLs, const float* __restrict__ t0buf,
    float* __restrict__ tstep)
{
  const int blk = blockIdx.x, tid = threadIdx.x;
  const float* rowL15 = rowLs + 15 * B;
  #pragma unroll
  for (int uu = 0; uu < 4; ++uu) {
    int flat = (blk * 1024 + uu * 256 + tid) * 4;
    int row = flat >> 14;
    float Rv = 1.0f / rowL15[row];
    u64 ev = *(const u64*)(eb15 + flat);
    f32x4 o;
    o[0] = bf2f((u16)ev) * Rv;
    o[1] = bf2f((u16)(ev >> 16)) * Rv;
    o[2] = bf2f((u16)(ev >> 32)) * Rv;
    o[3] = bf2f((u16)(ev >> 48)) * Rv;
    *(f32x4*)(out + (size_t)row * RWN + (size_t)15 * N + (flat & (N - 1))) = o;
  }
  if (blk == 0) {
    const int wave = tid >> 6, lane = tid & 63;
    __shared__ float redS[8];
    float tv = t0buf[tid];
    float v = tv;
    #pragma unroll
    for (int off = 1; off < 64; off <<= 1) v = fminf(v, __shfl_xor(v, off));
    if (lane == 0) redS[wave] = v;
    __syncthreads();
    float mn = fminf(fminf(redS[0], redS[1]), fminf(redS[2], redS[3]));
    if (mn < 0.1f) tv -= mn;
    v = tv;
    #pragma unroll
    for (int off = 1; off < 64; off <<= 1) v = fmaxf(v, __shfl_xor(v, off));
    if (lane == 0) redS[4 + wave] = v;
    __syncthreads();
    float mx = fmaxf(fmaxf(redS[4], redS[5]), fmaxf(redS[6], redS[7]));
    if (mx > 1.0f) tv /= mx;
    tv = fminf(fmaxf(tv, tstep[15 * B + tid]), 1.0f);
    tstep[16 * B + tid] = tv;
    out[TS_OFF + tid * RW + 15] = tv;
  }
}

__global__ __launch_bounds__(256) void k_prob(
    const float* __restrict__ Hgf15, const float* __restrict__ rowLs,
    const float* __restrict__ tstep, const float* __restrict__ Wt_up,
    const float* __restrict__ bt_up, const float* __restrict__ wpc,
    float* __restrict__ outp)
{
  int b = threadIdx.x;
  float R = 1.0f / rowLs[15 * B + b];
  float acc = 0.0f;
  for (int m = 0; m < HIN; ++m) acc += Hgf15[b * HIN + m] * R * wpc[m];
  float tv = tstep[16 * B + b];
  for (int j = 0; j < HT; ++j) acc += (tv * Wt_up[j] + bt_up[j]) * wpc[HIN + j];
  outp[b] = acc;
}

// ---------- launch ----------
extern "C" void kernel_launch(void* const* d_in, const int* in_sizes, int n_in,
                              void* d_out, int out_size, void* d_ws, size_t ws_size,
                              hipStream_t stream) {
  (void)in_sizes; (void)n_in; (void)out_size; (void)ws_size;
  const float* latent  = (const float*)d_in[0];
  const float* inputs0 = (const float*)d_in[1];
  const float* Wc      = (const float*)d_in[2];
  const float* bc      = (const float*)d_in[3];
  const float* Ws      = (const float*)d_in[4];
  const float* bs      = (const float*)d_in[5];
  const float* Wh      = (const float*)d_in[6];
  const float* bh      = (const float*)d_in[7];
  const float* Wcc     = (const float*)d_in[8];
  const float* bcc     = (const float*)d_in[9];
  const float* W_ih    = (const float*)d_in[10];
  const float* b_ih    = (const float*)d_in[11];
  const float* W_hh    = (const float*)d_in[12];
  const float* b_hh    = (const float*)d_in[13];
  const float* W_up    = (const float*)d_in[14];
  const float* b_up    = (const float*)d_in[15];
  const float* W_down  = (const float*)d_in[16];
  const float* Wt_down = (const float*)d_in[17];
  const float* bt_down = (const float*)d_in[18];
  const float* Wt_pred = (const float*)d_in[19];
  const float* Wt_up   = (const float*)d_in[20];
  const float* bt_up   = (const float*)d_in[21];
  const float* W_vt    = (const float*)d_in[22];
  const float* W_prob  = (const float*)d_in[23];
  const float* gumbel  = (const float*)d_in[24];
  const float* drop_u  = (const float*)d_in[25];
  float* out = (float*)d_out;

  char* p = (char*)d_ws;
  auto alloc = [&](size_t bytes) { char* r = p; p += (bytes + 255) & ~(size_t)255; return r; };
  u16*   Wup_b  = (u16*)  alloc((size_t)N * H * 2);
  u16*   Wdn_b  = (u16*)  alloc((size_t)HIN * N * 2);
  u16*   Wfull_b= (u16*)  alloc((size_t)4 * H * KC2 * 2);
  u16*   Wtd_b  = (u16*)  alloc((size_t)HT * H * 2);
  u16*   Whc_b  = (u16*)  alloc((size_t)2 * H * H * 2);
  float* bcomb  = (float*)alloc(4 * H * 4);
  u16*   hbuf0  = (u16*)  alloc((size_t)B * H * 2);
  u16*   hbuf1  = (u16*)  alloc((size_t)B * H * 2);
  float* cbuf   = (float*)alloc((size_t)B * H * 4);
  u16*   sinit_b= (u16*)  alloc((size_t)B * H * 2);
  float* latbuf = (float*)alloc((size_t)B * HIN * 4);
  float* rowLs  = (float*)alloc((size_t)16 * B * 4);
  float* t0buf  = (float*)alloc(B * 4);
  float* tstep  = (float*)alloc((size_t)17 * B * 4);
  float* Hgf2_0 = (float*)alloc((size_t)B * HIN * 4);
  float* Hgf2_1 = (float*)alloc((size_t)B * HIN * 4);
  float* g0add  = (float*)alloc((size_t)B * 4 * H * 4);
  float* wpc    = (float*)alloc(160 * 4);
  u16*   ebuf0  = (u16*)  alloc((size_t)B * N * 2);
  u16*   ebuf1  = (u16*)  alloc((size_t)B * N * 2);

  k_prep<<<2048, 256, 0, stream>>>(W_up, W_down, W_hh, Wt_down, b_ih, b_hh, Wh, Wcc,
                                   Wup_b, Wdn_b, Wfull_b, Wtd_b, Whc_b, bcomb,
                                   tstep, rowLs);
  k_fold<<<3330, 256, 0, stream>>>(W_ih, W_vt, inputs0, W_prob, Wfull_b, g0add, wpc);
  k_lat  <<<128, 256, 0, stream>>>(latent, Wc, bc, latbuf);
  k_sinit<<<512, 256, 0, stream>>>(latbuf, Ws, bs, sinit_b);
  k_h0c0m<<<1024, 256, 0, stream>>>(sinit_b, Whc_b, bh, bcc, cbuf, hbuf1);

  for (int r = 0; r < 16; ++r) {
    u16* hprev = (r & 1) ? hbuf0 : hbuf1;
    u16* hcur  = (r & 1) ? hbuf1 : hbuf0;
    u16* eb    = (r & 1) ? ebuf1 : ebuf0;
    u16* ebp   = (r & 1) ? ebuf0 : ebuf1;
    float* HgfCur  = (r & 1) ? Hgf2_1 : Hgf2_0;
    float* HgfPrev = (r & 1) ? Hgf2_0 : Hgf2_1;
    k_lstm2<<<512, 256, 0, stream>>>(hprev, hcur, Wfull_b, bcomb, cbuf, g0add,
                                     HgfPrev, HgfCur, rowLs, t0buf, tstep,
                                     Wt_up, bt_up, out, ebp, r);
    k_pgemm2<<<1024, 256, 0, stream>>>(hcur, Wup_b, b_up, gumbel + (size_t)r * B * N,
                                       eb, rowLs + r * B, HgfCur, Wdn_b,
                                       Wtd_b, bt_down, Wt_pred,
                                       drop_u + (size_t)r * B * HT, t0buf);
  }
  k_tail<<<1024, 256, 0, stream>>>(out, ebuf1, rowLs, t0buf, tstep);
  k_prob<<<1, 256, 0, stream>>>(Hgf2_1, rowLs, tstep, Wt_up, bt_up, wpc, out + PROB_OFF);
}